// Round 1
// 207.880 us; speedup vs baseline: 1.0501x; 1.0501x over previous
//
#include <hip/hip_runtime.h>
#include <stdint.h>

typedef unsigned short u16;
typedef __attribute__((ext_vector_type(8))) short bf16x8;
typedef __attribute__((ext_vector_type(4))) short bf16x4;
typedef __attribute__((ext_vector_type(4))) float f32x4;
typedef __attribute__((ext_vector_type(4))) unsigned short u16x4;

// async global->LDS, 16B per lane, dest = wave-uniform base + lane*16
#define GLD16(gp, lp) __builtin_amdgcn_global_load_lds( \
    (__attribute__((address_space(1))) void*)(void*)(gp), \
    (__attribute__((address_space(3))) void*)(void*)(lp), 16, 0, 0)

__device__ __forceinline__ u16 f2b(float f) {  // fp32 -> bf16 bits, RNE
  union { float f; unsigned u; } v; v.f = f;
  unsigned r = v.u + 0x7FFFu + ((v.u >> 16) & 1u);
  return (u16)(r >> 16);
}

__device__ __forceinline__ float fexp2(float x) {
#if __has_builtin(__builtin_amdgcn_exp2f)
  return __builtin_amdgcn_exp2f(x);
#else
  return exp2f(x);
#endif
}

// ---------------- weights fp32 -> bf16 (proj_w then out_w, one launch) ----
__global__ __launch_bounds__(256) void cvt_kernel(const float* __restrict__ wq_f,
                                                  const float* __restrict__ wo_f,
                                                  u16* __restrict__ wq,
                                                  u16* __restrict__ wo) {
  int i = blockIdx.x * 256 + threadIdx.x;   // 0 .. 262143
  const float* src; u16* dst; int j;
  if (i < 196608) { src = wq_f; dst = wq; j = i; }
  else            { src = wo_f; dst = wo; j = i - 196608; }
  const float4 f = ((const float4*)src)[j];
  u16x4 r; r[0] = f2b(f.x); r[1] = f2b(f.y); r[2] = f2b(f.z); r[3] = f2b(f.w);
  *(u16x4*)(dst + (size_t)j * 4) = r;
}

// ---------------- GroupNorm + transpose to h[B,S,C] bf16 ----------------
__global__ __launch_bounds__(256) void gn_kernel(const float* __restrict__ x,
                                                 const float* __restrict__ gw,
                                                 const float* __restrict__ gb,
                                                 u16* __restrict__ h) {
  const int b = blockIdx.x >> 5, g = blockIdx.x & 31;
  const float* xg = x + ((size_t)(b * 512 + g * 16)) * 1024;
  const int tid = threadIdx.x;
  float vals[64];
  float s = 0.f, ss = 0.f;
#pragma unroll
  for (int i = 0; i < 64; i++) {
    float vv = xg[i * 256 + tid];
    vals[i] = vv; s += vv; ss += vv * vv;
  }
#pragma unroll
  for (int off = 32; off; off >>= 1) { s += __shfl_down(s, off); ss += __shfl_down(ss, off); }
  __shared__ float red[8];
  const int wid = tid >> 6, lane = tid & 63;
  if (lane == 0) { red[wid] = s; red[4 + wid] = ss; }
  __syncthreads();
  if (tid == 0) {
    float S = red[0] + red[1] + red[2] + red[3];
    float SS = red[4] + red[5] + red[6] + red[7];
    float mean = S * (1.f / 16384.f);
    float var = SS * (1.f / 16384.f) - mean * mean;
    red[0] = mean; red[1] = rsqrtf(var + 1e-5f);
  }
  __syncthreads();
  const float mean = red[0], rs = red[1];
  float sc[16], bi[16];
#pragma unroll
  for (int c = 0; c < 16; c++) { sc[c] = gw[g * 16 + c] * rs; bi[c] = gb[g * 16 + c]; }
#pragma unroll
  for (int h4 = 0; h4 < 4; h4++) {
    const int sp = h4 * 256 + tid;
    u16 row[16];
#pragma unroll
    for (int c = 0; c < 16; c++)
      row[c] = f2b((vals[c * 4 + h4] - mean) * sc[c] + bi[c]);
    u16* dst = h + ((size_t)(b * 1024 + sp)) * 512 + g * 16;
    *(bf16x8*)dst = *(bf16x8*)&row[0];
    *(bf16x8*)(dst + 8) = *(bf16x8*)&row[8];
  }
}

// ---------------- QKV GEMM ----------------
// q,k stored [B,H,S,D]; v stored TRANSPOSED [B,H,D,S].
// q additionally carries log2(e) so attention can use exp2 directly.
__global__ __launch_bounds__(256) void qkv_gemm(const u16* __restrict__ h,
                                                const u16* __restrict__ w,
                                                const float* __restrict__ bias,
                                                u16* __restrict__ q,
                                                u16* __restrict__ k,
                                                u16* __restrict__ v) {
  __shared__ u16 As[128 * 32];
  __shared__ u16 Bs[128 * 32];
  const int b = blockIdx.z;
  const int bm = blockIdx.x;
  const int bn = blockIdx.y;
  const int tid = threadIdx.x, lane = tid & 63, wid = tid >> 6;
  const int wm = wid & 1, wn = wid >> 1;
  const u16* gA = h + ((size_t)b * 1024 + bm * 128) * 512;
  const u16* gB = w + (size_t)bn * 128 * 512;

  const f32x4 fz = {0.f, 0.f, 0.f, 0.f};
  f32x4 acc[4][4];
#pragma unroll
  for (int i = 0; i < 4; i++)
#pragma unroll
    for (int j = 0; j < 4; j++) acc[i][j] = fz;

  const int r0 = lane >> 2;
  const int ch8 = (lane & 3) * 8;

  for (int kt = 0; kt < 16; ++kt) {
    __syncthreads();
#pragma unroll
    for (int j = 0; j < 2; ++j) {
      const int idx = wid * 2 + j;
      const int row = idx * 16 + r0;
      GLD16(gA + (size_t)row * 512 + kt * 32 + ch8, &As[idx * 512 + lane * 8]);
      GLD16(gB + (size_t)row * 512 + kt * 32 + ch8, &Bs[idx * 512 + lane * 8]);
    }
    __syncthreads();
    bf16x8 af[4], bf[4];
#pragma unroll
    for (int mi = 0; mi < 4; mi++)
      af[mi] = *(const bf16x8*)&As[(wm * 64 + mi * 16 + (lane & 15)) * 32 + (lane >> 4) * 8];
#pragma unroll
    for (int ni = 0; ni < 4; ni++)
      bf[ni] = *(const bf16x8*)&Bs[(wn * 64 + ni * 16 + (lane & 15)) * 32 + (lane >> 4) * 8];
#pragma unroll
    for (int mi = 0; mi < 4; mi++)
#pragma unroll
      for (int ni = 0; ni < 4; ni++)
        acc[mi][ni] = __builtin_amdgcn_mfma_f32_16x16x32_bf16(af[mi], bf[ni], acc[mi][ni], 0, 0, 0);
  }

  const float qscale = 0.51006972f;            // 2^-1.5 * log2(e)
  const float kscale = 0.35355339059327373f;   // 2^-1.5
  const int quad4 = (lane >> 4) << 2;
#pragma unroll
  for (int mi = 0; mi < 4; mi++) {
    const int m = bm * 128 + wm * 64 + mi * 16 + quad4;
#pragma unroll
    for (int ni = 0; ni < 4; ni++) {
      const int n = bn * 128 + wn * 64 + ni * 16 + (lane & 15);
      const int head = n / 192;
      const int rr = n - head * 192;
      const float bi = bias[n];
      const int d = rr & 63;
      if (rr < 128) {
        u16* dst = (rr < 64) ? q : k;
        const float sc = (rr < 64) ? qscale : kscale;
        dst += ((size_t)(b * 8 + head) * 1024 + m) * 64 + d;
#pragma unroll
        for (int r = 0; r < 4; r++)
          dst[(size_t)r * 64] = f2b((acc[mi][ni][r] + bi) * sc);
      } else {
        u16x4 pk;
#pragma unroll
        for (int r = 0; r < 4; r++) pk[r] = f2b(acc[mi][ni][r] + bi);
        *(u16x4*)(v + ((size_t)(b * 8 + head) * 64 + d) * 1024 + m) = pk;
      }
    }
  }
}

// ---------------- flash attention v10: 8-wave / 256-Q-row blocks ----------
// grid = (B*H=128, S/256=4), 512 threads. Same double-buffered 64-key K/V
// LDS tiles as v9, but shared by 8 waves (256 Q rows) instead of 4 (128):
// staging bytes per MFMA halve, K/V global re-fetch per bh halves (4 blocks
// instead of 8). Per-thread staging drops to one bf16x8 of K + one of V.
// s_setprio(1) wraps the QK and PV MFMA clusters (T5).
__global__ __launch_bounds__(512) void attn_kernel(const u16* __restrict__ q,
                                                   const u16* __restrict__ k,
                                                   const u16* __restrict__ vT,
                                                   u16* __restrict__ o) {
  __shared__ u16 Ks[2][64 * 64];
  __shared__ u16 Vs[2][64 * 64];
  const int bh = blockIdx.x;
  const int qb = blockIdx.y;      // 0..3
  const int tid = threadIdx.x, lane = tid & 63, wid = tid >> 6;   // wid 0..7
  const u16* Q = q + (size_t)bh * 1024 * 64;
  const u16* K = k + (size_t)bh * 1024 * 64;
  const u16* V = vT + (size_t)bh * 64 * 1024;
  const int qrow0 = qb * 256 + wid * 32;
  const int c15 = lane & 15, quad = lane >> 4;
  const int sw = c15 & 7;                  // read-side swizzle component
  // staging: thread t -> row srow (key-row for K, d for V), 16B = 8 cols
  const int srow = tid >> 3;               // 0..63
  const int u8g  = tid & 7;                // 8-col group (K) / 8-key group (V)
  const int s7 = srow & 7;
  const int kld = srow * 64 + ((u8g ^ s7) * 8);
  // V permuted-key layout: key-chunk kc (4 keys) lives at position-chunk
  // pc = 8*(kc>>3) + 2*((kc&7)&3) + ((kc&7)>>2). Thread stages kc=2u,2u+1:
  // pc0 = 8*(u>>2)+4*(u&1)+((u>>1)&1), pc1 = pc0+2 (verified vs v9 mapping).
  const int ve = 4 * (u8g >> 2) + 2 * (u8g & 1);   // pc0>>1
  const int vc = ((u8g >> 1) & 1) * 4;             // (pc0&1)*4
  const int vld0 = srow * 64 + ((ve ^ s7) * 8) + vc;
  const int vld1 = srow * 64 + (((ve + 1) ^ s7) * 8) + vc;

  // Q as B-operand frags for QK: B[n = ni*16+c15][k = kk*32+quad*8]
  bf16x8 qf[2][2];
#pragma unroll
  for (int kk = 0; kk < 2; kk++)
#pragma unroll
    for (int ni = 0; ni < 2; ni++)
      qf[kk][ni] = *(const bf16x8*)(Q + (size_t)(qrow0 + ni * 16 + c15) * 64 + kk * 32 + quad * 8);

  const f32x4 fz = {0.f, 0.f, 0.f, 0.f};
  const float Mshift = 14.4269504089f;     // 10 * log2(e)
  const f32x4 fm = {-Mshift, -Mshift, -Mshift, -Mshift};
  f32x4 oaccT[4][2];               // O^T[d-tile nd][qrow-tile ni]
#pragma unroll
  for (int i = 0; i < 4; i++)
#pragma unroll
    for (int j = 0; j < 2; j++) oaccT[i][j] = fz;
  float lsum[2] = {0.f, 0.f};

  // prologue: tile 0 regs -> buf0; prefetch tile 1 into regs
  bf16x8 kr, vr;
  kr = *(const bf16x8*)(K + (size_t)srow * 64 + u8g * 8);
  vr = *(const bf16x8*)(V + (size_t)srow * 1024 + u8g * 8);
  {
    u16* Kd = Ks[0]; u16* Vd = Vs[0];
    *(bf16x8*)&Kd[kld] = kr;
    union { bf16x4 h[2]; bf16x8 v; } a; a.v = vr;
    *(bf16x4*)&Vd[vld0] = a.h[0];
    *(bf16x4*)&Vd[vld1] = a.h[1];
  }
  kr = *(const bf16x8*)(K + (size_t)(64 + srow) * 64 + u8g * 8);
  vr = *(const bf16x8*)(V + (size_t)srow * 1024 + 64 + u8g * 8);

  for (int kt = 0; kt < 16; ++kt) {
    __syncthreads();   // publish buf[kt&1]; retire readers of buf[(kt&1)^1]
    const int cur = kt & 1, alt = cur ^ 1;
    if (kt < 15) {
      // store tile kt+1 into alt (overlaps compute on cur)
      u16* Kd = Ks[alt]; u16* Vd = Vs[alt];
      *(bf16x8*)&Kd[kld] = kr;
      union { bf16x4 h[2]; bf16x8 v; } a; a.v = vr;
      *(bf16x4*)&Vd[vld0] = a.h[0];
      *(bf16x4*)&Vd[vld1] = a.h[1];
      // prefetch tile kt+2 into regs (wraps harmlessly at the end)
      const int pk2 = (kt + 2) & 15;
      kr = *(const bf16x8*)(K + ((size_t)pk2 * 64 + srow) * 64 + u8g * 8);
      vr = *(const bf16x8*)(V + (size_t)srow * 1024 + pk2 * 64 + u8g * 8);
    }
    const u16* Kc = Ks[cur];
    const u16* Vc = Vs[cur];

    // S^T = K Q^T (D[m=key][n=qrow]), accumulator pre-seeded with -M
    f32x4 sacc[4][2];
#pragma unroll
    for (int i = 0; i < 4; i++)
#pragma unroll
      for (int j = 0; j < 2; j++) sacc[i][j] = fm;
#pragma unroll
    for (int kk = 0; kk < 2; kk++) {
      bf16x8 af[4];
#pragma unroll
      for (int mi = 0; mi < 4; mi++)
        af[mi] = *(const bf16x8*)&Kc[(mi * 16 + c15) * 64 + (((kk * 4 + quad) ^ sw) * 8)];
      __builtin_amdgcn_s_setprio(1);
#pragma unroll
      for (int mi = 0; mi < 4; mi++)
#pragma unroll
        for (int ni = 0; ni < 2; ni++)
          sacc[mi][ni] = __builtin_amdgcn_mfma_f32_16x16x32_bf16(af[mi], qf[kk][ni], sacc[mi][ni], 0, 0, 0);
      __builtin_amdgcn_s_setprio(0);
    }

    // P = exp2(s') packed to bf16 pairs IN REGISTERS (truncation);
    // per-lane l partials (fp32, pre-truncation)
    unsigned pkd[4][2][2];   // [key-tile mi][ni][dword]
#pragma unroll
    for (int ni = 0; ni < 2; ni++) {
      float ls = 0.f;
#pragma unroll
      for (int mi = 0; mi < 4; mi++) {
        unsigned pu[4];
#pragma unroll
        for (int r = 0; r < 4; r++) {
          const float p = fexp2(sacc[mi][ni][r]);
          ls += p;
          union { float f; unsigned u; } c; c.f = p;
          pu[r] = c.u;
        }
        pkd[mi][ni][0] = __builtin_amdgcn_perm(pu[1], pu[0], 0x07060302u);
        pkd[mi][ni][1] = __builtin_amdgcn_perm(pu[3], pu[2], 0x07060302u);
      }
      lsum[ni] += ls;
    }

    // O^T += V^T P^T : A = b128 from permuted Vs, B = packed P registers.
#pragma unroll
    for (int mg = 0; mg < 2; mg++) {
      union { unsigned u[4]; bf16x8 v; } bb[2];
#pragma unroll
      for (int ni = 0; ni < 2; ni++) {
        bb[ni].u[0] = pkd[2 * mg][ni][0];     bb[ni].u[1] = pkd[2 * mg][ni][1];
        bb[ni].u[2] = pkd[2 * mg + 1][ni][0]; bb[ni].u[3] = pkd[2 * mg + 1][ni][1];
      }
      bf16x8 aa[4];
#pragma unroll
      for (int nd = 0; nd < 4; nd++)
        aa[nd] = *(const bf16x8*)&Vc[(nd * 16 + c15) * 64 + (((mg * 4 + quad) ^ sw) * 8)];
      __builtin_amdgcn_s_setprio(1);
#pragma unroll
      for (int nd = 0; nd < 4; nd++)
#pragma unroll
        for (int ni = 0; ni < 2; ni++)
          oaccT[nd][ni] = __builtin_amdgcn_mfma_f32_16x16x32_bf16(aa[nd], bb[ni].v, oaccT[nd][ni], 0, 0, 0);
      __builtin_amdgcn_s_setprio(0);
    }
  }

  // final l reduction; lane already owns its qrows' O^T columns (n=c15)
  float iv[2];
#pragma unroll
  for (int ni = 0; ni < 2; ni++) {
    float l = lsum[ni];
    l += __shfl_xor(l, 16);
    l += __shfl_xor(l, 32);
    iv[ni] = 1.f / l;
  }
  const int b = bh >> 3, hh = bh & 7;
#pragma unroll
  for (int ni = 0; ni < 2; ni++) {
    const int row = qrow0 + ni * 16 + c15;
#pragma unroll
    for (int nd = 0; nd < 4; nd++) {
      u16x4 pk4;
#pragma unroll
      for (int r = 0; r < 4; r++) pk4[r] = f2b(oaccT[nd][ni][r] * iv[ni]);
      *(u16x4*)(o + ((size_t)b * 1024 + row) * 512 + hh * 64 + nd * 16 + quad * 4) = pk4;
    }
  }
}

// ---------------- out proj (operands swapped: D[c][s]) + bias + residual ----------------
__global__ __launch_bounds__(256) void out_gemm(const u16* __restrict__ wo,
                                                const u16* __restrict__ attn,
                                                const float* __restrict__ ob,
                                                const float* __restrict__ x,
                                                float* __restrict__ out) {
  __shared__ u16 As[128 * 32];
  __shared__ u16 Bs[128 * 32];
  const int b = blockIdx.z;
  const int bm = blockIdx.x;
  const int bn = blockIdx.y;
  const int tid = threadIdx.x, lane = tid & 63, wid = tid >> 6;
  const int wm = wid & 1, wn = wid >> 1;
  const u16* gA = wo + (size_t)bm * 128 * 512;
  const u16* gB = attn + ((size_t)b * 1024 + bn * 128) * 512;

  const f32x4 fz = {0.f, 0.f, 0.f, 0.f};
  f32x4 acc[4][4];
#pragma unroll
  for (int i = 0; i < 4; i++)
#pragma unroll
    for (int j = 0; j < 4; j++) acc[i][j] = fz;

  const int r0 = lane >> 2;
  const int ch8 = (lane & 3) * 8;

  for (int kt = 0; kt < 16; ++kt) {
    __syncthreads();
#pragma unroll
    for (int j = 0; j < 2; ++j) {
      const int idx = wid * 2 + j;
      const int row = idx * 16 + r0;
      GLD16(gA + (size_t)row * 512 + kt * 32 + ch8, &As[idx * 512 + lane * 8]);
      GLD16(gB + (size_t)row * 512 + kt * 32 + ch8, &Bs[idx * 512 + lane * 8]);
    }
    __syncthreads();
    bf16x8 af[4], bf[4];
#pragma unroll
    for (int mi = 0; mi < 4; mi++)
      af[mi] = *(const bf16x8*)&As[(wm * 64 + mi * 16 + (lane & 15)) * 32 + (lane >> 4) * 8];
#pragma unroll
    for (int ni = 0; ni < 4; ni++)
      bf[ni] = *(const bf16x8*)&Bs[(wn * 64 + ni * 16 + (lane & 15)) * 32 + (lane >> 4) * 8];
#pragma unroll
    for (int mi = 0; mi < 4; mi++)
#pragma unroll
      for (int ni = 0; ni < 4; ni++)
        acc[mi][ni] = __builtin_amdgcn_mfma_f32_16x16x32_bf16(af[mi], bf[ni], acc[mi][ni], 0, 0, 0);
  }

  const int quad4 = (lane >> 4) << 2;
#pragma unroll
  for (int mi = 0; mi < 4; mi++) {
    const int c = bm * 128 + wm * 64 + mi * 16 + quad4;
#pragma unroll
    for (int ni = 0; ni < 4; ni++) {
      const int s = bn * 128 + wn * 64 + ni * 16 + (lane & 15);
#pragma unroll
      for (int r = 0; r < 4; r++) {
        const int cc = c + r;
        const size_t idx = ((size_t)b * 512 + cc) * 1024 + s;
        out[idx] = acc[mi][ni][r] + ob[cc] + x[idx];
      }
    }
  }
}

extern "C" void kernel_launch(void* const* d_in, const int* in_sizes, int n_in,
                              void* d_out, int out_size, void* d_ws, size_t ws_size,
                              hipStream_t stream) {
  const float* x      = (const float*)d_in[0];
  const float* gn_w   = (const float*)d_in[1];
  const float* gn_b   = (const float*)d_in[2];
  const float* proj_w = (const float*)d_in[3];
  const float* proj_b = (const float*)d_in[4];
  const float* out_w  = (const float*)d_in[5];
  const float* out_b  = (const float*)d_in[6];
  float* out = (float*)d_out;

  char* p = (char*)d_ws;
  u16* h    = (u16*)p; p += (size_t)16 * 1024 * 512 * 2;
  u16* q    = (u16*)p; p += (size_t)16 * 8 * 1024 * 64 * 2;
  u16* k    = (u16*)p; p += (size_t)16 * 8 * 1024 * 64 * 2;
  u16* v    = (u16*)p; p += (size_t)16 * 8 * 1024 * 64 * 2;   // [B,H,D,S]
  u16* attn = (u16*)p; p += (size_t)16 * 1024 * 512 * 2;
  u16* wq   = (u16*)p; p += (size_t)1536 * 512 * 2;
  u16* wo   = (u16*)p; p += (size_t)512 * 512 * 2;

  cvt_kernel<<<1024, 256, 0, stream>>>(proj_w, out_w, wq, wo);
  gn_kernel<<<512, 256, 0, stream>>>(x, gn_w, gn_b, h);
  qkv_gemm<<<dim3(8, 12, 16), 256, 0, stream>>>(h, wq, proj_b, q, k, v);
  attn_kernel<<<dim3(128, 4), 512, 0, stream>>>(q, k, v, attn);
  out_gemm<<<dim3(4, 8, 16), 256, 0, stream>>>(wo, attn, out_b, x, out);
}

// Round 2
// 207.761 us; speedup vs baseline: 1.0507x; 1.0006x over previous
//
#include <hip/hip_runtime.h>
#include <stdint.h>

typedef unsigned short u16;
typedef __attribute__((ext_vector_type(8))) short bf16x8;
typedef __attribute__((ext_vector_type(4))) short bf16x4;
typedef __attribute__((ext_vector_type(4))) float f32x4;
typedef __attribute__((ext_vector_type(4))) unsigned short u16x4;

// async global->LDS, 16B per lane, dest = wave-uniform base + lane*16
#define GLD16(gp, lp) __builtin_amdgcn_global_load_lds( \
    (__attribute__((address_space(1))) void*)(void*)(gp), \
    (__attribute__((address_space(3))) void*)(void*)(lp), 16, 0, 0)

__device__ __forceinline__ u16 f2b(float f) {  // fp32 -> bf16 bits, RNE
  union { float f; unsigned u; } v; v.f = f;
  unsigned r = v.u + 0x7FFFu + ((v.u >> 16) & 1u);
  return (u16)(r >> 16);
}

__device__ __forceinline__ float fexp2(float x) {
#if __has_builtin(__builtin_amdgcn_exp2f)
  return __builtin_amdgcn_exp2f(x);
#else
  return exp2f(x);
#endif
}

// ---------------- weights fp32 -> bf16 (proj_w then out_w, one launch) ----
__global__ __launch_bounds__(256) void cvt_kernel(const float* __restrict__ wq_f,
                                                  const float* __restrict__ wo_f,
                                                  u16* __restrict__ wq,
                                                  u16* __restrict__ wo) {
  int i = blockIdx.x * 256 + threadIdx.x;   // 0 .. 262143
  const float* src; u16* dst; int j;
  if (i < 196608) { src = wq_f; dst = wq; j = i; }
  else            { src = wo_f; dst = wo; j = i - 196608; }
  const float4 f = ((const float4*)src)[j];
  u16x4 r; r[0] = f2b(f.x); r[1] = f2b(f.y); r[2] = f2b(f.z); r[3] = f2b(f.w);
  *(u16x4*)(dst + (size_t)j * 4) = r;
}

// ---------------- GroupNorm + transpose to h[B,S,C] bf16 ----------------
__global__ __launch_bounds__(256) void gn_kernel(const float* __restrict__ x,
                                                 const float* __restrict__ gw,
                                                 const float* __restrict__ gb,
                                                 u16* __restrict__ h) {
  const int b = blockIdx.x >> 5, g = blockIdx.x & 31;
  const float* xg = x + ((size_t)(b * 512 + g * 16)) * 1024;
  const int tid = threadIdx.x;
  float vals[64];
  float s = 0.f, ss = 0.f;
#pragma unroll
  for (int i = 0; i < 64; i++) {
    float vv = xg[i * 256 + tid];
    vals[i] = vv; s += vv; ss += vv * vv;
  }
#pragma unroll
  for (int off = 32; off; off >>= 1) { s += __shfl_down(s, off); ss += __shfl_down(ss, off); }
  __shared__ float red[8];
  const int wid = tid >> 6, lane = tid & 63;
  if (lane == 0) { red[wid] = s; red[4 + wid] = ss; }
  __syncthreads();
  if (tid == 0) {
    float S = red[0] + red[1] + red[2] + red[3];
    float SS = red[4] + red[5] + red[6] + red[7];
    float mean = S * (1.f / 16384.f);
    float var = SS * (1.f / 16384.f) - mean * mean;
    red[0] = mean; red[1] = rsqrtf(var + 1e-5f);
  }
  __syncthreads();
  const float mean = red[0], rs = red[1];
  float sc[16], bi[16];
#pragma unroll
  for (int c = 0; c < 16; c++) { sc[c] = gw[g * 16 + c] * rs; bi[c] = gb[g * 16 + c]; }
#pragma unroll
  for (int h4 = 0; h4 < 4; h4++) {
    const int sp = h4 * 256 + tid;
    u16 row[16];
#pragma unroll
    for (int c = 0; c < 16; c++)
      row[c] = f2b((vals[c * 4 + h4] - mean) * sc[c] + bi[c]);
    u16* dst = h + ((size_t)(b * 1024 + sp)) * 512 + g * 16;
    *(bf16x8*)dst = *(bf16x8*)&row[0];
    *(bf16x8*)(dst + 8) = *(bf16x8*)&row[8];
  }
}

// ---------------- QKV GEMM v2: 256x128 tile, BK=64, phase-split ----------
// M=16384 (B*S), N=1536, K=512. grid (64,12) = 768 blocks = 3 exact rounds.
// 512 threads = 8 waves (4M x 2N), per-wave 64x64 output, acc[4][4].
// Double-buffered 96KB LDS staged via global_load_lds (6x16B/thread/K-tile),
// issued one K-tile ahead inside phase 1 (issue-early, T14/T3 principle).
// Raw s_barrier + sched_barrier(0) (NO __syncthreads -> no vmcnt(0) drain at
// phase barriers); single vmcnt(0) per K-tile right before the buffer swap.
// LDS XOR swizzle (T2): phys chunk p holds logical chunk p^(row&7); reads use
// (kk*4+quad)^(c15&7) -> quarter-wave b128 reads spread all 32 banks.
// s_setprio(1) around each 16-MFMA cluster (T5).
__global__ __launch_bounds__(512, 2) void qkv_gemm(const u16* __restrict__ h,
                                                   const u16* __restrict__ w,
                                                   const float* __restrict__ bias,
                                                   u16* __restrict__ q,
                                                   u16* __restrict__ k,
                                                   u16* __restrict__ v) {
  __shared__ u16 As[2][256 * 64];   // 64 KB
  __shared__ u16 Bs[2][128 * 64];   // 32 KB
  const int bm = blockIdx.x;        // 0..63
  const int bn = blockIdx.y;        // 0..11
  const int tid = threadIdx.x, lane = tid & 63, wid = tid >> 6;
  const int wm = wid >> 1, wn = wid & 1;     // 4M x 2N waves, 64x64 each
  const int c15 = lane & 15, quad = lane >> 4;
  const int sw = c15 & 7;                    // read-side swizzle
  const u16* gA = h + (size_t)bm * 256 * 512;
  const u16* gB = w + (size_t)bn * 128 * 512;

  // staging: thread -> (row = r*64 + sr, phys-chunk tid&7); source chunk is
  // pre-swizzled so that phys chunk p receives logical chunk p^(row&7).
  const int sr = tid >> 3;                   // 0..63
  const int lch = (tid & 7) ^ (sr & 7);
  const u16* sA = gA + (size_t)sr * 512 + lch * 8;
  const u16* sB = gB + (size_t)sr * 512 + lch * 8;
  const int sdst = tid * 8;                  // u16 offset within a round

  const f32x4 fz = {0.f, 0.f, 0.f, 0.f};
  f32x4 acc[4][4];
#pragma unroll
  for (int i = 0; i < 4; i++)
#pragma unroll
    for (int j = 0; j < 4; j++) acc[i][j] = fz;

  // prologue: stage K-tile 0 into buffer 0, wait, sync
#pragma unroll
  for (int r = 0; r < 4; r++)
    GLD16(sA + (size_t)r * 32768, &As[0][r * 4096 + sdst]);
#pragma unroll
  for (int r = 0; r < 2; r++)
    GLD16(sB + (size_t)r * 32768, &Bs[0][r * 4096 + sdst]);
  asm volatile("s_waitcnt vmcnt(0)" ::: "memory");
  __builtin_amdgcn_s_barrier();
  __builtin_amdgcn_sched_barrier(0);

  for (int kt = 0; kt < 8; ++kt) {
    const int c = kt & 1, d = c ^ 1;
    // ---- phase 1: issue next tile's staging, read A frags + B frags(ni0,1)
    if (kt < 7) {
      const size_t ko = (size_t)(kt + 1) * 64;
#pragma unroll
      for (int r = 0; r < 4; r++)
        GLD16(sA + (size_t)r * 32768 + ko, &As[d][r * 4096 + sdst]);
#pragma unroll
      for (int r = 0; r < 2; r++)
        GLD16(sB + (size_t)r * 32768 + ko, &Bs[d][r * 4096 + sdst]);
    }
    bf16x8 af[2][4], bfx[2][2];
#pragma unroll
    for (int kk = 0; kk < 2; kk++) {
      const int kc = ((kk * 4 + quad) ^ sw) * 8;
#pragma unroll
      for (int mi = 0; mi < 4; mi++)
        af[kk][mi] = *(const bf16x8*)&As[c][(wm * 64 + mi * 16 + c15) * 64 + kc];
#pragma unroll
      for (int ni = 0; ni < 2; ni++)
        bfx[kk][ni] = *(const bf16x8*)&Bs[c][(wn * 64 + ni * 16 + c15) * 64 + kc];
    }
    __builtin_amdgcn_s_barrier();
    __builtin_amdgcn_sched_barrier(0);
    __builtin_amdgcn_s_setprio(1);
#pragma unroll
    for (int kk = 0; kk < 2; kk++)
#pragma unroll
      for (int mi = 0; mi < 4; mi++)
#pragma unroll
        for (int ni = 0; ni < 2; ni++)
          acc[mi][ni] = __builtin_amdgcn_mfma_f32_16x16x32_bf16(af[kk][mi], bfx[kk][ni], acc[mi][ni], 0, 0, 0);
    __builtin_amdgcn_s_setprio(0);
    __builtin_amdgcn_s_barrier();
    __builtin_amdgcn_sched_barrier(0);
    // ---- phase 2: read B frags(ni2,3), compute
#pragma unroll
    for (int kk = 0; kk < 2; kk++) {
      const int kc = ((kk * 4 + quad) ^ sw) * 8;
#pragma unroll
      for (int ni = 0; ni < 2; ni++)
        bfx[kk][ni] = *(const bf16x8*)&Bs[c][(wn * 64 + (2 + ni) * 16 + c15) * 64 + kc];
    }
    __builtin_amdgcn_s_barrier();
    __builtin_amdgcn_sched_barrier(0);
    __builtin_amdgcn_s_setprio(1);
#pragma unroll
    for (int kk = 0; kk < 2; kk++)
#pragma unroll
      for (int mi = 0; mi < 4; mi++)
#pragma unroll
        for (int ni = 0; ni < 2; ni++)
          acc[mi][2 + ni] = __builtin_amdgcn_mfma_f32_16x16x32_bf16(af[kk][mi], bfx[kk][ni], acc[mi][2 + ni], 0, 0, 0);
    __builtin_amdgcn_s_setprio(0);
    if (kt < 7) asm volatile("s_waitcnt vmcnt(0)" ::: "memory");
    __builtin_amdgcn_s_barrier();
    __builtin_amdgcn_sched_barrier(0);
  }

  const float qscale = 0.51006972f;            // 2^-1.5 * log2(e)
  const float kscale = 0.35355339059327373f;   // 2^-1.5
  const int quad4 = quad << 2;
#pragma unroll
  for (int mi = 0; mi < 4; mi++) {
    const int m = bm * 256 + wm * 64 + mi * 16 + quad4;   // global row
    const int b = m >> 10, sp = m & 1023;
#pragma unroll
    for (int ni = 0; ni < 4; ni++) {
      const int n = bn * 128 + wn * 64 + ni * 16 + c15;
      const int head = n / 192;
      const int rr = n - head * 192;
      const float bi = bias[n];
      const int d = rr & 63;
      if (rr < 128) {
        u16* dst = (rr < 64) ? q : k;
        const float sc = (rr < 64) ? qscale : kscale;
        dst += ((size_t)(b * 8 + head) * 1024 + sp) * 64 + d;
#pragma unroll
        for (int r = 0; r < 4; r++)
          dst[(size_t)r * 64] = f2b((acc[mi][ni][r] + bi) * sc);
      } else {
        u16x4 pk;
#pragma unroll
        for (int r = 0; r < 4; r++) pk[r] = f2b(acc[mi][ni][r] + bi);
        *(u16x4*)(v + ((size_t)(b * 8 + head) * 64 + d) * 1024 + sp) = pk;
      }
    }
  }
}

// ---------------- flash attention v10: 8-wave / 256-Q-row blocks ----------
__global__ __launch_bounds__(512) void attn_kernel(const u16* __restrict__ q,
                                                   const u16* __restrict__ k,
                                                   const u16* __restrict__ vT,
                                                   u16* __restrict__ o) {
  __shared__ u16 Ks[2][64 * 64];
  __shared__ u16 Vs[2][64 * 64];
  const int bh = blockIdx.x;
  const int qb = blockIdx.y;      // 0..3
  const int tid = threadIdx.x, lane = tid & 63, wid = tid >> 6;   // wid 0..7
  const u16* Q = q + (size_t)bh * 1024 * 64;
  const u16* K = k + (size_t)bh * 1024 * 64;
  const u16* V = vT + (size_t)bh * 64 * 1024;
  const int qrow0 = qb * 256 + wid * 32;
  const int c15 = lane & 15, quad = lane >> 4;
  const int sw = c15 & 7;                  // read-side swizzle component
  const int srow = tid >> 3;               // 0..63
  const int u8g  = tid & 7;                // 8-col group (K) / 8-key group (V)
  const int s7 = srow & 7;
  const int kld = srow * 64 + ((u8g ^ s7) * 8);
  const int ve = 4 * (u8g >> 2) + 2 * (u8g & 1);   // pc0>>1
  const int vc = ((u8g >> 1) & 1) * 4;             // (pc0&1)*4
  const int vld0 = srow * 64 + ((ve ^ s7) * 8) + vc;
  const int vld1 = srow * 64 + (((ve + 1) ^ s7) * 8) + vc;

  bf16x8 qf[2][2];
#pragma unroll
  for (int kk = 0; kk < 2; kk++)
#pragma unroll
    for (int ni = 0; ni < 2; ni++)
      qf[kk][ni] = *(const bf16x8*)(Q + (size_t)(qrow0 + ni * 16 + c15) * 64 + kk * 32 + quad * 8);

  const f32x4 fz = {0.f, 0.f, 0.f, 0.f};
  const float Mshift = 14.4269504089f;     // 10 * log2(e)
  const f32x4 fm = {-Mshift, -Mshift, -Mshift, -Mshift};
  f32x4 oaccT[4][2];               // O^T[d-tile nd][qrow-tile ni]
#pragma unroll
  for (int i = 0; i < 4; i++)
#pragma unroll
    for (int j = 0; j < 2; j++) oaccT[i][j] = fz;
  float lsum[2] = {0.f, 0.f};

  bf16x8 kr, vr;
  kr = *(const bf16x8*)(K + (size_t)srow * 64 + u8g * 8);
  vr = *(const bf16x8*)(V + (size_t)srow * 1024 + u8g * 8);
  {
    u16* Kd = Ks[0]; u16* Vd = Vs[0];
    *(bf16x8*)&Kd[kld] = kr;
    union { bf16x4 h[2]; bf16x8 v; } a; a.v = vr;
    *(bf16x4*)&Vd[vld0] = a.h[0];
    *(bf16x4*)&Vd[vld1] = a.h[1];
  }
  kr = *(const bf16x8*)(K + (size_t)(64 + srow) * 64 + u8g * 8);
  vr = *(const bf16x8*)(V + (size_t)srow * 1024 + 64 + u8g * 8);

  for (int kt = 0; kt < 16; ++kt) {
    __syncthreads();   // publish buf[kt&1]; retire readers of buf[(kt&1)^1]
    const int cur = kt & 1, alt = cur ^ 1;
    if (kt < 15) {
      u16* Kd = Ks[alt]; u16* Vd = Vs[alt];
      *(bf16x8*)&Kd[kld] = kr;
      union { bf16x4 h[2]; bf16x8 v; } a; a.v = vr;
      *(bf16x4*)&Vd[vld0] = a.h[0];
      *(bf16x4*)&Vd[vld1] = a.h[1];
      const int pk2 = (kt + 2) & 15;
      kr = *(const bf16x8*)(K + ((size_t)pk2 * 64 + srow) * 64 + u8g * 8);
      vr = *(const bf16x8*)(V + (size_t)srow * 1024 + pk2 * 64 + u8g * 8);
    }
    const u16* Kc = Ks[cur];
    const u16* Vc = Vs[cur];

    f32x4 sacc[4][2];
#pragma unroll
    for (int i = 0; i < 4; i++)
#pragma unroll
      for (int j = 0; j < 2; j++) sacc[i][j] = fm;
#pragma unroll
    for (int kk = 0; kk < 2; kk++) {
      bf16x8 af[4];
#pragma unroll
      for (int mi = 0; mi < 4; mi++)
        af[mi] = *(const bf16x8*)&Kc[(mi * 16 + c15) * 64 + (((kk * 4 + quad) ^ sw) * 8)];
      __builtin_amdgcn_s_setprio(1);
#pragma unroll
      for (int mi = 0; mi < 4; mi++)
#pragma unroll
        for (int ni = 0; ni < 2; ni++)
          sacc[mi][ni] = __builtin_amdgcn_mfma_f32_16x16x32_bf16(af[mi], qf[kk][ni], sacc[mi][ni], 0, 0, 0);
      __builtin_amdgcn_s_setprio(0);
    }

    unsigned pkd[4][2][2];   // [key-tile mi][ni][dword]
#pragma unroll
    for (int ni = 0; ni < 2; ni++) {
      float ls = 0.f;
#pragma unroll
      for (int mi = 0; mi < 4; mi++) {
        unsigned pu[4];
#pragma unroll
        for (int r = 0; r < 4; r++) {
          const float p = fexp2(sacc[mi][ni][r]);
          ls += p;
          union { float f; unsigned u; } c; c.f = p;
          pu[r] = c.u;
        }
        pkd[mi][ni][0] = __builtin_amdgcn_perm(pu[1], pu[0], 0x07060302u);
        pkd[mi][ni][1] = __builtin_amdgcn_perm(pu[3], pu[2], 0x07060302u);
      }
      lsum[ni] += ls;
    }

#pragma unroll
    for (int mg = 0; mg < 2; mg++) {
      union { unsigned u[4]; bf16x8 v; } bb[2];
#pragma unroll
      for (int ni = 0; ni < 2; ni++) {
        bb[ni].u[0] = pkd[2 * mg][ni][0];     bb[ni].u[1] = pkd[2 * mg][ni][1];
        bb[ni].u[2] = pkd[2 * mg + 1][ni][0]; bb[ni].u[3] = pkd[2 * mg + 1][ni][1];
      }
      bf16x8 aa[4];
#pragma unroll
      for (int nd = 0; nd < 4; nd++)
        aa[nd] = *(const bf16x8*)&Vc[(nd * 16 + c15) * 64 + (((mg * 4 + quad) ^ sw) * 8)];
      __builtin_amdgcn_s_setprio(1);
#pragma unroll
      for (int nd = 0; nd < 4; nd++)
#pragma unroll
        for (int ni = 0; ni < 2; ni++)
          oaccT[nd][ni] = __builtin_amdgcn_mfma_f32_16x16x32_bf16(aa[nd], bb[ni].v, oaccT[nd][ni], 0, 0, 0);
      __builtin_amdgcn_s_setprio(0);
    }
  }

  float iv[2];
#pragma unroll
  for (int ni = 0; ni < 2; ni++) {
    float l = lsum[ni];
    l += __shfl_xor(l, 16);
    l += __shfl_xor(l, 32);
    iv[ni] = 1.f / l;
  }
  const int b = bh >> 3, hh = bh & 7;
#pragma unroll
  for (int ni = 0; ni < 2; ni++) {
    const int row = qrow0 + ni * 16 + c15;
#pragma unroll
    for (int nd = 0; nd < 4; nd++) {
      u16x4 pk4;
#pragma unroll
      for (int r = 0; r < 4; r++) pk4[r] = f2b(oaccT[nd][ni][r] * iv[ni]);
      *(u16x4*)(o + ((size_t)b * 1024 + row) * 512 + hh * 64 + nd * 16 + quad * 4) = pk4;
    }
  }
}

// ---------------- out proj (operands swapped: D[c][s]) + bias + residual ----------------
__global__ __launch_bounds__(256) void out_gemm(const u16* __restrict__ wo,
                                                const u16* __restrict__ attn,
                                                const float* __restrict__ ob,
                                                const float* __restrict__ x,
                                                float* __restrict__ out) {
  __shared__ u16 As[128 * 32];
  __shared__ u16 Bs[128 * 32];
  const int b = blockIdx.z;
  const int bm = blockIdx.x;
  const int bn = blockIdx.y;
  const int tid = threadIdx.x, lane = tid & 63, wid = tid >> 6;
  const int wm = wid & 1, wn = wid >> 1;
  const u16* gA = wo + (size_t)bm * 128 * 512;
  const u16* gB = attn + ((size_t)b * 1024 + bn * 128) * 512;

  const f32x4 fz = {0.f, 0.f, 0.f, 0.f};
  f32x4 acc[4][4];
#pragma unroll
  for (int i = 0; i < 4; i++)
#pragma unroll
    for (int j = 0; j < 4; j++) acc[i][j] = fz;

  const int r0 = lane >> 2;
  const int ch8 = (lane & 3) * 8;

  for (int kt = 0; kt < 16; ++kt) {
    __syncthreads();
#pragma unroll
    for (int j = 0; j < 2; ++j) {
      const int idx = wid * 2 + j;
      const int row = idx * 16 + r0;
      GLD16(gA + (size_t)row * 512 + kt * 32 + ch8, &As[idx * 512 + lane * 8]);
      GLD16(gB + (size_t)row * 512 + kt * 32 + ch8, &Bs[idx * 512 + lane * 8]);
    }
    __syncthreads();
    bf16x8 af[4], bf[4];
#pragma unroll
    for (int mi = 0; mi < 4; mi++)
      af[mi] = *(const bf16x8*)&As[(wm * 64 + mi * 16 + (lane & 15)) * 32 + (lane >> 4) * 8];
#pragma unroll
    for (int ni = 0; ni < 4; ni++)
      bf[ni] = *(const bf16x8*)&Bs[(wn * 64 + ni * 16 + (lane & 15)) * 32 + (lane >> 4) * 8];
#pragma unroll
    for (int mi = 0; mi < 4; mi++)
#pragma unroll
      for (int ni = 0; ni < 4; ni++)
        acc[mi][ni] = __builtin_amdgcn_mfma_f32_16x16x32_bf16(af[mi], bf[ni], acc[mi][ni], 0, 0, 0);
  }

  const int quad4 = (lane >> 4) << 2;
#pragma unroll
  for (int mi = 0; mi < 4; mi++) {
    const int c = bm * 128 + wm * 64 + mi * 16 + quad4;
#pragma unroll
    for (int ni = 0; ni < 4; ni++) {
      const int s = bn * 128 + wn * 64 + ni * 16 + (lane & 15);
#pragma unroll
      for (int r = 0; r < 4; r++) {
        const int cc = c + r;
        const size_t idx = ((size_t)b * 512 + cc) * 1024 + s;
        out[idx] = acc[mi][ni][r] + ob[cc] + x[idx];
      }
    }
  }
}

extern "C" void kernel_launch(void* const* d_in, const int* in_sizes, int n_in,
                              void* d_out, int out_size, void* d_ws, size_t ws_size,
                              hipStream_t stream) {
  const float* x      = (const float*)d_in[0];
  const float* gn_w   = (const float*)d_in[1];
  const float* gn_b   = (const float*)d_in[2];
  const float* proj_w = (const float*)d_in[3];
  const float* proj_b = (const float*)d_in[4];
  const float* out_w  = (const float*)d_in[5];
  const float* out_b  = (const float*)d_in[6];
  float* out = (float*)d_out;

  char* p = (char*)d_ws;
  u16* h    = (u16*)p; p += (size_t)16 * 1024 * 512 * 2;
  u16* q    = (u16*)p; p += (size_t)16 * 8 * 1024 * 64 * 2;
  u16* k    = (u16*)p; p += (size_t)16 * 8 * 1024 * 64 * 2;
  u16* v    = (u16*)p; p += (size_t)16 * 8 * 1024 * 64 * 2;   // [B,H,D,S]
  u16* attn = (u16*)p; p += (size_t)16 * 1024 * 512 * 2;
  u16* wq   = (u16*)p; p += (size_t)1536 * 512 * 2;
  u16* wo   = (u16*)p; p += (size_t)512 * 512 * 2;

  cvt_kernel<<<1024, 256, 0, stream>>>(proj_w, out_w, wq, wo);
  gn_kernel<<<512, 256, 0, stream>>>(x, gn_w, gn_b, h);
  qkv_gemm<<<dim3(64, 12), 512, 0, stream>>>(h, wq, proj_b, q, k, v);
  attn_kernel<<<dim3(128, 4), 512, 0, stream>>>(q, k, v, attn);
  out_gemm<<<dim3(4, 8, 16), 256, 0, stream>>>(wo, attn, out_b, x, out);
}